// Round 6
// baseline (228.260 us; speedup 1.0000x reference)
//
#include <hip/hip_runtime.h>
#include <hip/hip_bf16.h>
#include <math.h>

#define S_LEN 2048
#define HID 2048
#define NH 32
#define NKV 8
#define HD 64
#define WINDOW 1024
#define QBLK 128
#define QKVN 3072   // fused Q(2048) | K(512) | V(512) columns

typedef __attribute__((ext_vector_type(8))) short bx8;          // 8 bf16 (4 VGPRs) — MFMA A/B frag
typedef __attribute__((ext_vector_type(4))) float fx4;          // MFMA C/D frag
typedef __attribute__((ext_vector_type(8))) unsigned short us8; // 8 bf16 raw

#define GL_LDS16(gp, lp) \
    __builtin_amdgcn_global_load_lds((__attribute__((address_space(1))) const void*)(gp), \
                                     (__attribute__((address_space(3))) void*)(lp), 16, 0, 0)

__device__ __forceinline__ float bf2f(unsigned short u) {
    return __uint_as_float(((unsigned)u) << 16);
}

// ---------------- RoPE tables (f64 on device, tiny) ----------------
__global__ void rope_table_kernel(float* __restrict__ cosT, float* __restrict__ sinT) {
    int idx = blockIdx.x * blockDim.x + threadIdx.x;  // s*32 + f
    if (idx >= S_LEN * 32) return;
    int s = idx >> 5, f = idx & 31;
    double inv = exp(-2.0 * (double)f / 64.0 * log(500000.0));
    double ang = (double)s * inv;
    cosT[idx] = (float)cos(ang);
    sinT[idx] = (float)sin(ang);
}

// ---------------- f32 -> bf16 elementwise ----------------
__global__ void conv_kernel(const float* __restrict__ in, __hip_bfloat16* __restrict__ out) {
    int i = (blockIdx.x * 256 + threadIdx.x) * 8;
    float4 a = *reinterpret_cast<const float4*>(&in[i]);
    float4 b = *reinterpret_cast<const float4*>(&in[i + 4]);
    __hip_bfloat16 o[8] __attribute__((aligned(16)));
    o[0] = __float2bfloat16(a.x); o[1] = __float2bfloat16(a.y);
    o[2] = __float2bfloat16(a.z); o[3] = __float2bfloat16(a.w);
    o[4] = __float2bfloat16(b.x); o[5] = __float2bfloat16(b.y);
    o[6] = __float2bfloat16(b.z); o[7] = __float2bfloat16(b.w);
    *reinterpret_cast<bx8*>(&out[i]) = *reinterpret_cast<bx8*>(o);
}

// ---------------- transpose+convert: out[n][k](bf16) = in[k][n](f32) ----------------
__global__ void convT_kernel(const float* __restrict__ in, __hip_bfloat16* __restrict__ out,
                             int K, int N, int outStride) {
    __shared__ float tile[32][33];
    int n0 = blockIdx.x * 32, k0 = blockIdx.y * 32;
    int tx = threadIdx.x, ty = threadIdx.y;  // 32 x 8
#pragma unroll
    for (int i = 0; i < 4; i++)
        tile[ty + 8 * i][tx] = in[(size_t)(k0 + ty + 8 * i) * N + n0 + tx];
    __syncthreads();
#pragma unroll
    for (int i = 0; i < 4; i++)
        out[(size_t)(n0 + ty + 8 * i) * outStride + k0 + tx] = __float2bfloat16(tile[tx][ty + 8 * i]);
}

// ---------------- bf16 transpose: Vt[d][s] = QKV[s][2560+d] ----------------
__global__ void vtrans_kernel(const __hip_bfloat16* __restrict__ QKV, __hip_bfloat16* __restrict__ Vt) {
    __shared__ __hip_bfloat16 tile[32][33];
    int s0 = blockIdx.x * 32, d0 = blockIdx.y * 32;
    int tx = threadIdx.x, ty = threadIdx.y;  // 32 x 8
#pragma unroll
    for (int i = 0; i < 4; i++)
        tile[ty + 8 * i][tx] = QKV[(size_t)(s0 + ty + 8 * i) * QKVN + 2560 + d0 + tx];
    __syncthreads();
#pragma unroll
    for (int i = 0; i < 4; i++)
        Vt[(size_t)(d0 + ty + 8 * i) * S_LEN + s0 + tx] = tile[tx][ty + 8 * i];
}

// ---------------- pipelined bf16 MFMA GEMM (frozen from R5) ----------------
template <int OUTBF16>
__global__ __launch_bounds__(256) void gemm_pipe_kernel(const __hip_bfloat16* __restrict__ A,
                                                        const __hip_bfloat16* __restrict__ Bt,
                                                        void* __restrict__ Cp,
                                                        int M, int N, int K, int nbx) {
    __shared__ __hip_bfloat16 As[3][4096];
    __shared__ __hip_bfloat16 Bs[3][4096];

    const int nwg = gridDim.x, cpx = nwg >> 3, bid = blockIdx.x;
    const int swz = (bid & 7) * cpx + (bid >> 3);
    const int bm = (swz / nbx) * 128, bn = (swz % nbx) * 128;

    const int t = threadIdx.x, w = t >> 6, l = t & 63;
    const int wr = (w >> 1) * 64, wc = (w & 1) * 64;
    const int lr = l & 15, lk = (l >> 4) * 8;
    const int srow = w * 16 + (l >> 2);
    const int scol = (l & 3) * 8;
    const int ldsoff = w * 512;

    const __hip_bfloat16* ga0 = A + (size_t)(bm + srow) * K + scol;
    const __hip_bfloat16* gb0 = Bt + (size_t)(bn + srow) * K + scol;
    const size_t half = (size_t)64 * K;

    fx4 acc[4][4];
#pragma unroll
    for (int m = 0; m < 4; m++)
#pragma unroll
        for (int n = 0; n < 4; n++) acc[m][n] = (fx4){0.f, 0.f, 0.f, 0.f};

    const int T = K >> 5;

#define STAGE(kt, b)                                              \
    do {                                                          \
        const __hip_bfloat16* ga = ga0 + (kt) * 32;               \
        const __hip_bfloat16* gb = gb0 + (kt) * 32;               \
        GL_LDS16(ga,        &As[(b)][ldsoff]);                    \
        GL_LDS16(ga + half, &As[(b)][2048 + ldsoff]);             \
        GL_LDS16(gb,        &Bs[(b)][ldsoff]);                    \
        GL_LDS16(gb + half, &Bs[(b)][2048 + ldsoff]);             \
    } while (0)

    STAGE(0, 0);
    STAGE(1, 1);

    for (int i = 0; i < T; i++) {
        const int r = i % 3;
        if (i + 1 < T) asm volatile("s_waitcnt vmcnt(4)" ::: "memory");
        else           asm volatile("s_waitcnt vmcnt(0)" ::: "memory");
        __builtin_amdgcn_s_barrier();
        asm volatile("" ::: "memory");
        if (i + 2 < T) STAGE(i + 2, (i + 2) % 3);

        bx8 af[4], bf[4];
#pragma unroll
        for (int m = 0; m < 4; m++)
            af[m] = *reinterpret_cast<const bx8*>(&As[r][(wr + m * 16 + lr) * 32 + lk]);
#pragma unroll
        for (int n = 0; n < 4; n++)
            bf[n] = *reinterpret_cast<const bx8*>(&Bs[r][(wc + n * 16 + lr) * 32 + lk]);
#pragma unroll
        for (int m = 0; m < 4; m++)
#pragma unroll
            for (int n = 0; n < 4; n++)
                acc[m][n] = __builtin_amdgcn_mfma_f32_16x16x32_bf16(af[m], bf[n], acc[m][n], 0, 0, 0);
    }
#undef STAGE

    const int lq = (l >> 4) * 4;
#pragma unroll
    for (int m = 0; m < 4; m++)
#pragma unroll
        for (int n = 0; n < 4; n++)
#pragma unroll
            for (int r2 = 0; r2 < 4; r2++) {
                int row = bm + wr + m * 16 + lq + r2;
                int col = bn + wc + n * 16 + lr;
                float v = acc[m][n][r2];
                if (OUTBF16)
                    ((__hip_bfloat16*)Cp)[(size_t)row * N + col] = __float2bfloat16(v);
                else
                    ((float*)Cp)[(size_t)row * N + col] = v;
            }
}

// ---------------- RoPE in-place on K columns of fused QKV (Q roped inside attn) ----------------
__global__ void ropek_kernel(__hip_bfloat16* __restrict__ QKV,
                             const float* __restrict__ cosT, const float* __restrict__ sinT) {
    int idx = blockIdx.x * blockDim.x + threadIdx.x;  // s*(8*32) + head*32 + f
    int f = idx & 31;
    int head = (idx >> 5) & 7;
    int s = idx >> 8;
    if (s >= S_LEN) return;
    float c  = cosT[(s << 5) + f];
    float sn = sinT[(s << 5) + f];
    __hip_bfloat16* p = QKV + (size_t)s * QKVN + 2048 + head * HD;
    float x1 = __bfloat162float(p[f]), x2 = __bfloat162float(p[f + 32]);
    p[f]      = __float2bfloat16(x1 * c - x2 * sn);
    p[f + 32] = __float2bfloat16(x2 * c + x1 * sn);
}

// ---------------- MFMA sliding-window flash attention ----------------
// R6: Q-RoPE+scale folded into prologue; T14 async staging; interior-tile mask
// skip; defer-max (THR=8).
__global__ __launch_bounds__(256) void attn_kernel(const __hip_bfloat16* __restrict__ Q,
                                                   const __hip_bfloat16* __restrict__ Kg,
                                                   const __hip_bfloat16* __restrict__ Vtg,
                                                   const float* __restrict__ cosT,
                                                   const float* __restrict__ sinT,
                                                   __hip_bfloat16* __restrict__ O) {
    __shared__ __hip_bfloat16 Ks[64 * 64];
    __shared__ __hip_bfloat16 Vs[64 * 64];
    __shared__ __hip_bfloat16 Ps[QBLK * 64];

    const int bid = blockIdx.x;
    const int swz = (bid & 7) * 64 + (bid >> 3);
    const int h = swz >> 4, qi = swz & 15;
    const int qb = qi * QBLK;
    const int kvh = h >> 2;

    const int t = threadIdx.x, w = t >> 6, l = t & 63;
    const int lr = l & 15, g = l >> 4, lk = g * 8;
    const int qbw = qb + 32 * w;

    char* KsB = (char*)Ks;
    char* VsB = (char*)Vs;
    char* PsB = (char*)Ps;

    // ---- prologue: load Q frags, apply RoPE + 0.125 scale in-register ----
    bx8 qa[2][2];
#pragma unroll
    for (int mf = 0; mf < 2; mf++) {
        const int rowq = qbw + 16 * mf + lr;
        us8 raw0 = *reinterpret_cast<const us8*>(&Q[(size_t)rowq * QKVN + h * HD + lk]);
        us8 raw1 = *reinterpret_cast<const us8*>(&Q[(size_t)rowq * QKVN + h * HD + 32 + lk]);
        const float* cp = &cosT[(rowq << 5) + lk];
        const float* sp = &sinT[(rowq << 5) + lk];
        float4 c0 = *reinterpret_cast<const float4*>(cp);
        float4 c1 = *reinterpret_cast<const float4*>(cp + 4);
        float4 s0 = *reinterpret_cast<const float4*>(sp);
        float4 s1 = *reinterpret_cast<const float4*>(sp + 4);
        float cc[8] = {c0.x, c0.y, c0.z, c0.w, c1.x, c1.y, c1.z, c1.w};
        float ss[8] = {s0.x, s0.y, s0.z, s0.w, s1.x, s1.y, s1.z, s1.w};
        __hip_bfloat16 o0[8] __attribute__((aligned(16)));
        __hip_bfloat16 o1[8] __attribute__((aligned(16)));
#pragma unroll
        for (int j = 0; j < 8; j++) {
            float x1 = bf2f(raw0[j]), x2 = bf2f(raw1[j]);
            o0[j] = __float2bfloat16((x1 * cc[j] - x2 * ss[j]) * 0.125f);
            o1[j] = __float2bfloat16((x2 * cc[j] + x1 * ss[j]) * 0.125f);
        }
        qa[mf][0] = *reinterpret_cast<bx8*>(o0);
        qa[mf][1] = *reinterpret_cast<bx8*>(o1);
    }

    fx4 o[2][4];
    float mrow[2][4], srow[2][4];
#pragma unroll
    for (int mf = 0; mf < 2; mf++)
#pragma unroll
        for (int n = 0; n < 4; n++) o[mf][n] = (fx4){0.f, 0.f, 0.f, 0.f};
#pragma unroll
    for (int mf = 0; mf < 2; mf++)
#pragma unroll
        for (int r = 0; r < 4; r++) { mrow[mf][r] = -1e30f; srow[mf][r] = 0.f; }

    const int k0_first = (qb >= 1024) ? (qb - 1024) : 0;
    const int k0_last  = qb + 64;
    const int wmax = qbw + 31;

    // staging addresses (per thread)
    const int sr0 = t >> 3, sc8 = (t & 7) * 8;          // j=0 row/col
    const int sr1 = (t + 256) >> 3;                     // j=1 row
    const int d0 = sr0 * 128 + ((sc8 * 2) ^ ((sr0 & 7) << 4));
    const int d1 = sr1 * 128 + ((sc8 * 2) ^ ((sr1 & 7) << 4));

    us8 kreg0, kreg1, vreg0, vreg1;
#define LOADT(k0)                                                                              \
    do {                                                                                       \
        kreg0 = *reinterpret_cast<const us8*>(&Kg[(size_t)((k0) + sr0) * QKVN + kvh * HD + sc8]); \
        kreg1 = *reinterpret_cast<const us8*>(&Kg[(size_t)((k0) + sr1) * QKVN + kvh * HD + sc8]); \
        vreg0 = *reinterpret_cast<const us8*>(&Vtg[(size_t)(kvh * HD + sr0) * S_LEN + (k0) + sc8]); \
        vreg1 = *reinterpret_cast<const us8*>(&Vtg[(size_t)(kvh * HD + sr1) * S_LEN + (k0) + sc8]); \
    } while (0)

    LOADT(k0_first);

    for (int k0 = k0_first; k0 <= k0_last; k0 += 64) {
        // write staged regs -> LDS
        *reinterpret_cast<us8*>(KsB + d0) = kreg0;
        *reinterpret_cast<us8*>(KsB + d1) = kreg1;
        *reinterpret_cast<us8*>(VsB + d0) = vreg0;
        *reinterpret_cast<us8*>(VsB + d1) = vreg1;
        __syncthreads();
        if (k0 + 64 <= k0_last) LOADT(k0 + 64);   // issue next-tile loads; land during compute

        if (k0 <= wmax) {
            const bool interior = (k0 + 63 <= qbw) && (k0 >= qbw - 992);
            bx8 kb[4][2];
#pragma unroll
            for (int n = 0; n < 4; n++)
#pragma unroll
                for (int ks = 0; ks < 2; ks++) {
                    int row = 16 * n + lr;
                    kb[n][ks] = *reinterpret_cast<const bx8*>(
                        KsB + row * 128 + (((ks * 64) + 16 * g) ^ ((row & 7) << 4)));
                }
#pragma unroll
            for (int mf = 0; mf < 2; mf++) {
                fx4 sc[4];
#pragma unroll
                for (int n = 0; n < 4; n++) {
                    sc[n] = __builtin_amdgcn_mfma_f32_16x16x32_bf16(qa[mf][0], kb[n][0],
                                                                    (fx4){0.f, 0.f, 0.f, 0.f}, 0, 0, 0);
                    sc[n] = __builtin_amdgcn_mfma_f32_16x16x32_bf16(qa[mf][1], kb[n][1], sc[n], 0, 0, 0);
                }
                if (!interior) {
#pragma unroll
                    for (int n = 0; n < 4; n++) {
                        int col = k0 + 16 * n + lr;
#pragma unroll
                        for (int r = 0; r < 4; r++) {
                            int rowq = qbw + 16 * mf + 4 * g + r;
                            bool valid = (col <= rowq) && (col >= rowq - (WINDOW - 1));
                            if (!valid) sc[n][r] = -1e30f;
                        }
                    }
                }
                float tm[4];
                bool need = false;
#pragma unroll
                for (int r = 0; r < 4; r++) {
                    float tmax = fmaxf(fmaxf(sc[0][r], sc[1][r]), fmaxf(sc[2][r], sc[3][r]));
                    tmax = fmaxf(tmax, __shfl_xor(tmax, 1));
                    tmax = fmaxf(tmax, __shfl_xor(tmax, 2));
                    tmax = fmaxf(tmax, __shfl_xor(tmax, 4));
                    tmax = fmaxf(tmax, __shfl_xor(tmax, 8));
                    tm[r] = tmax;
                    need = need || (tmax > mrow[mf][r] + 8.f);
                }
                if (__any(need)) {
#pragma unroll
                    for (int r = 0; r < 4; r++) {
                        float mo = mrow[mf][r];
                        float mn = fmaxf(mo, tm[r]);
                        float fs = __expf(mo - mn);
                        mrow[mf][r] = mn;
                        srow[mf][r] *= fs;
#pragma unroll
                        for (int n = 0; n < 4; n++) o[mf][n][r] *= fs;
                    }
                }
#pragma unroll
                for (int r = 0; r < 4; r++) {
                    float ps = 0.f;
#pragma unroll
                    for (int n = 0; n < 4; n++) {
                        float p = __expf(sc[n][r] - mrow[mf][r]);
                        sc[n][r] = p;
                        ps += p;
                    }
                    ps += __shfl_xor(ps, 1);
                    ps += __shfl_xor(ps, 2);
                    ps += __shfl_xor(ps, 4);
                    ps += __shfl_xor(ps, 8);
                    srow[mf][r] += ps;
                }
#pragma unroll
                for (int r = 0; r < 4; r++) {
                    int prow = 32 * w + 16 * mf + 4 * g + r;
                    char* pb = PsB + prow * 128;
                    int sz = (prow & 7) << 4;
#pragma unroll
                    for (int n = 0; n < 4; n++)
                        *reinterpret_cast<__hip_bfloat16*>(pb + (((16 * n + lr) * 2) ^ sz)) =
                            __float2bfloat16(sc[n][r]);
                }
            }
            bx8 vb[4][2];
#pragma unroll
            for (int n = 0; n < 4; n++)
#pragma unroll
                for (int ks = 0; ks < 2; ks++) {
                    int row = 16 * n + lr;
                    vb[n][ks] = *reinterpret_cast<const bx8*>(
                        VsB + row * 128 + (((ks * 64) + 16 * g) ^ ((row & 7) << 4)));
                }
#pragma unroll
            for (int mf = 0; mf < 2; mf++) {
                bx8 pa[2];
#pragma unroll
                for (int ks = 0; ks < 2; ks++) {
                    int prow = 32 * w + 16 * mf + lr;
                    pa[ks] = *reinterpret_cast<const bx8*>(
                        PsB + prow * 128 + (((ks * 64) + 16 * g) ^ ((prow & 7) << 4)));
                }
#pragma unroll
                for (int n = 0; n < 4; n++) {
                    o[mf][n] = __builtin_amdgcn_mfma_f32_16x16x32_bf16(pa[0], vb[n][0], o[mf][n], 0, 0, 0);
                    o[mf][n] = __builtin_amdgcn_mfma_f32_16x16x32_bf16(pa[1], vb[n][1], o[mf][n], 0, 0, 0);
                }
            }
        }
        __syncthreads();
    }
#undef LOADT

#pragma unroll
    for (int mf = 0; mf < 2; mf++) {
        float inv[4];
#pragma unroll
        for (int r = 0; r < 4; r++) inv[r] = 1.f / srow[mf][r];
#pragma unroll
        for (int n = 0; n < 4; n++)
#pragma unroll
            for (int r = 0; r < 4; r++) {
                int rq = qbw + 16 * mf + 4 * g + r;
                O[(size_t)rq * HID + h * HD + 16 * n + lr] = __float2bfloat16(o[mf][n][r] * inv[r]);
            }
    }
}

extern "C" void kernel_launch(void* const* d_in, const int* in_sizes, int n_in,
                              void* d_out, int out_size, void* d_ws, size_t ws_size,
                              hipStream_t stream) {
    const float* hs = (const float*)d_in[0];
    const float* Wq = (const float*)d_in[1];
    const float* Wk = (const float*)d_in[2];
    const float* Wv = (const float*)d_in[3];
    const float* Wo = (const float*)d_in[4];

    float* ws   = (float*)d_ws;
    float* cosT = ws;                  // 65536 f32
    float* sinT = cosT + 65536;        // 65536 f32
    __hip_bfloat16* hsb    = (__hip_bfloat16*)(sinT + 65536);   // [2048][2048]
    __hip_bfloat16* WqkvT  = hsb + 4194304;                     // [3072][2048]: Wq|Wk|Wv rows
    __hip_bfloat16* WoT    = WqkvT + 6291456;                   // [2048][2048]
    __hip_bfloat16* QKVb   = WoT + 4194304;                     // [2048][3072]
    __hip_bfloat16* Vt     = QKVb + 6291456;                    // [512][2048]
    __hip_bfloat16* Ab     = hsb;                               // alias: hsb dead after QKV gemm

    rope_table_kernel<<<(S_LEN * 32) / 256, 256, 0, stream>>>(cosT, sinT);
    conv_kernel<<<2048, 256, 0, stream>>>(hs, hsb);
    convT_kernel<<<dim3(64, 64), dim3(32, 8), 0, stream>>>(Wq, WqkvT, 2048, 2048, 2048);
    convT_kernel<<<dim3(16, 64), dim3(32, 8), 0, stream>>>(Wk, WqkvT + (size_t)2048 * 2048, 2048, 512, 2048);
    convT_kernel<<<dim3(16, 64), dim3(32, 8), 0, stream>>>(Wv, WqkvT + (size_t)2560 * 2048, 2048, 512, 2048);
    convT_kernel<<<dim3(64, 64), dim3(32, 8), 0, stream>>>(Wo, WoT, 2048, 2048, 2048);

    // fused QKV projection: [2048][3072] = hsb @ WqkvT^T
    gemm_pipe_kernel<1><<<384, 256, 0, stream>>>(hsb, WqkvT, QKVb, 2048, QKVN, 2048, 24);

    // RoPE on K only (Q roped inside attn; V needs none)
    ropek_kernel<<<2048, 256, 0, stream>>>(QKVb, cosT, sinT);

    vtrans_kernel<<<dim3(64, 16), dim3(32, 8), 0, stream>>>(QKVb, Vt);

    attn_kernel<<<512, 256, 0, stream>>>(QKVb, QKVb + 2048, Vt, cosT, sinT, Ab);

    // output projection: d_out = Ab @ WoT^T
    gemm_pipe_kernel<0><<<256, 256, 0, stream>>>(Ab, WoT, d_out, 2048, 2048, 2048, 16);
}

// Round 7
// 188.904 us; speedup vs baseline: 1.2083x; 1.2083x over previous
//
#include <hip/hip_runtime.h>
#include <hip/hip_bf16.h>
#include <math.h>

#define S_LEN 2048
#define HID 2048
#define NH 32
#define NKV 8
#define HD 64
#define WINDOW 1024
#define QBLK 128
#define QKVN 3072   // fused Q(2048) | K(512) | V(512) columns

typedef __attribute__((ext_vector_type(8))) short bx8;          // 8 bf16 (4 VGPRs) — MFMA A/B frag
typedef __attribute__((ext_vector_type(4))) float fx4;          // MFMA C/D frag
typedef __attribute__((ext_vector_type(8))) unsigned short us8; // 8 bf16 raw

#define GL_LDS16(gp, lp) \
    __builtin_amdgcn_global_load_lds((__attribute__((address_space(1))) const void*)(gp), \
                                     (__attribute__((address_space(3))) void*)(lp), 16, 0, 0)

// ---------------- RoPE tables (f64 on device, tiny) ----------------
__global__ void rope_table_kernel(float* __restrict__ cosT, float* __restrict__ sinT) {
    int idx = blockIdx.x * blockDim.x + threadIdx.x;  // s*32 + f
    if (idx >= S_LEN * 32) return;
    int s = idx >> 5, f = idx & 31;
    double inv = exp(-2.0 * (double)f / 64.0 * log(500000.0));
    double ang = (double)s * inv;
    cosT[idx] = (float)cos(ang);
    sinT[idx] = (float)sin(ang);
}

// ---------------- f32 -> bf16 elementwise ----------------
__global__ void conv_kernel(const float* __restrict__ in, __hip_bfloat16* __restrict__ out) {
    int i = (blockIdx.x * 256 + threadIdx.x) * 8;
    float4 a = *reinterpret_cast<const float4*>(&in[i]);
    float4 b = *reinterpret_cast<const float4*>(&in[i + 4]);
    __hip_bfloat16 o[8] __attribute__((aligned(16)));
    o[0] = __float2bfloat16(a.x); o[1] = __float2bfloat16(a.y);
    o[2] = __float2bfloat16(a.z); o[3] = __float2bfloat16(a.w);
    o[4] = __float2bfloat16(b.x); o[5] = __float2bfloat16(b.y);
    o[6] = __float2bfloat16(b.z); o[7] = __float2bfloat16(b.w);
    *reinterpret_cast<bx8*>(&out[i]) = *reinterpret_cast<bx8*>(o);
}

// ---------------- transpose+convert: out[n][k](bf16) = in[k][n](f32) ----------------
__global__ void convT_kernel(const float* __restrict__ in, __hip_bfloat16* __restrict__ out,
                             int K, int N, int outStride) {
    __shared__ float tile[32][33];
    int n0 = blockIdx.x * 32, k0 = blockIdx.y * 32;
    int tx = threadIdx.x, ty = threadIdx.y;  // 32 x 8
#pragma unroll
    for (int i = 0; i < 4; i++)
        tile[ty + 8 * i][tx] = in[(size_t)(k0 + ty + 8 * i) * N + n0 + tx];
    __syncthreads();
#pragma unroll
    for (int i = 0; i < 4; i++)
        out[(size_t)(n0 + ty + 8 * i) * outStride + k0 + tx] = __float2bfloat16(tile[tx][ty + 8 * i]);
}

// ---------------- bf16 transpose: Vt[d][s] = QKV[s][2560+d] ----------------
__global__ void vtrans_kernel(const __hip_bfloat16* __restrict__ QKV, __hip_bfloat16* __restrict__ Vt) {
    __shared__ __hip_bfloat16 tile[32][33];
    int s0 = blockIdx.x * 32, d0 = blockIdx.y * 32;
    int tx = threadIdx.x, ty = threadIdx.y;  // 32 x 8
#pragma unroll
    for (int i = 0; i < 4; i++)
        tile[ty + 8 * i][tx] = QKV[(size_t)(s0 + ty + 8 * i) * QKVN + 2560 + d0 + tx];
    __syncthreads();
#pragma unroll
    for (int i = 0; i < 4; i++)
        Vt[(size_t)(d0 + ty + 8 * i) * S_LEN + s0 + tx] = tile[tx][ty + 8 * i];
}

// ---------------- pipelined bf16 MFMA GEMM (frozen from R5) ----------------
template <int OUTBF16>
__global__ __launch_bounds__(256) void gemm_pipe_kernel(const __hip_bfloat16* __restrict__ A,
                                                        const __hip_bfloat16* __restrict__ Bt,
                                                        void* __restrict__ Cp,
                                                        int M, int N, int K, int nbx) {
    __shared__ __hip_bfloat16 As[3][4096];
    __shared__ __hip_bfloat16 Bs[3][4096];

    const int nwg = gridDim.x, cpx = nwg >> 3, bid = blockIdx.x;
    const int swz = (bid & 7) * cpx + (bid >> 3);
    const int bm = (swz / nbx) * 128, bn = (swz % nbx) * 128;

    const int t = threadIdx.x, w = t >> 6, l = t & 63;
    const int wr = (w >> 1) * 64, wc = (w & 1) * 64;
    const int lr = l & 15, lk = (l >> 4) * 8;
    const int srow = w * 16 + (l >> 2);
    const int scol = (l & 3) * 8;
    const int ldsoff = w * 512;

    const __hip_bfloat16* ga0 = A + (size_t)(bm + srow) * K + scol;
    const __hip_bfloat16* gb0 = Bt + (size_t)(bn + srow) * K + scol;
    const size_t half = (size_t)64 * K;

    fx4 acc[4][4];
#pragma unroll
    for (int m = 0; m < 4; m++)
#pragma unroll
        for (int n = 0; n < 4; n++) acc[m][n] = (fx4){0.f, 0.f, 0.f, 0.f};

    const int T = K >> 5;

#define STAGE(kt, b)                                              \
    do {                                                          \
        const __hip_bfloat16* ga = ga0 + (kt) * 32;               \
        const __hip_bfloat16* gb = gb0 + (kt) * 32;               \
        GL_LDS16(ga,        &As[(b)][ldsoff]);                    \
        GL_LDS16(ga + half, &As[(b)][2048 + ldsoff]);             \
        GL_LDS16(gb,        &Bs[(b)][ldsoff]);                    \
        GL_LDS16(gb + half, &Bs[(b)][2048 + ldsoff]);             \
    } while (0)

    STAGE(0, 0);
    STAGE(1, 1);

    for (int i = 0; i < T; i++) {
        const int r = i % 3;
        if (i + 1 < T) asm volatile("s_waitcnt vmcnt(4)" ::: "memory");
        else           asm volatile("s_waitcnt vmcnt(0)" ::: "memory");
        __builtin_amdgcn_s_barrier();
        asm volatile("" ::: "memory");
        if (i + 2 < T) STAGE(i + 2, (i + 2) % 3);

        bx8 af[4], bf[4];
#pragma unroll
        for (int m = 0; m < 4; m++)
            af[m] = *reinterpret_cast<const bx8*>(&As[r][(wr + m * 16 + lr) * 32 + lk]);
#pragma unroll
        for (int n = 0; n < 4; n++)
            bf[n] = *reinterpret_cast<const bx8*>(&Bs[r][(wc + n * 16 + lr) * 32 + lk]);
#pragma unroll
        for (int m = 0; m < 4; m++)
#pragma unroll
            for (int n = 0; n < 4; n++)
                acc[m][n] = __builtin_amdgcn_mfma_f32_16x16x32_bf16(af[m], bf[n], acc[m][n], 0, 0, 0);
    }
#undef STAGE

    const int lq = (l >> 4) * 4;
#pragma unroll
    for (int m = 0; m < 4; m++)
#pragma unroll
        for (int n = 0; n < 4; n++)
#pragma unroll
            for (int r2 = 0; r2 < 4; r2++) {
                int row = bm + wr + m * 16 + lq + r2;
                int col = bn + wc + n * 16 + lr;
                float v = acc[m][n][r2];
                if (OUTBF16)
                    ((__hip_bfloat16*)Cp)[(size_t)row * N + col] = __float2bfloat16(v);
                else
                    ((float*)Cp)[(size_t)row * N + col] = v;
            }
}

// ---------------- RoPE in-place on fused QKV [S][3072] (Q cols 0-2047, K cols 2048-2559) ----------------
__global__ void rope_kernel(__hip_bfloat16* __restrict__ QKV,
                            const float* __restrict__ cosT, const float* __restrict__ sinT) {
    int idx = blockIdx.x * blockDim.x + threadIdx.x;  // s*(40*32) + head*32 + f
    int f = idx & 31;
    int head = (idx >> 5) % (NH + NKV);
    int s = idx / ((NH + NKV) * 32);
    if (s >= S_LEN) return;
    float c  = cosT[(s << 5) + f];
    float sn = sinT[(s << 5) + f];
    __hip_bfloat16* p = (head < NH) ? (QKV + (size_t)s * QKVN + head * HD)
                                    : (QKV + (size_t)s * QKVN + 2048 + (head - NH) * HD);
    float x1 = __bfloat162float(p[f]), x2 = __bfloat162float(p[f + 32]);
    p[f]      = __float2bfloat16(x1 * c - x2 * sn);
    p[f + 32] = __float2bfloat16(x2 * c + x1 * sn);
}

// ---------------- MFMA sliding-window flash attention ----------------
// R7: R5 inner loop verbatim, re-partitioned to 8 waves x 16 q-rows (512 thr)
// to double resident waves 8->16/CU. One m-frag per wave.
__global__ __launch_bounds__(512, 4) void attn_kernel(const __hip_bfloat16* __restrict__ Q,
                                                      const __hip_bfloat16* __restrict__ Kg,
                                                      const __hip_bfloat16* __restrict__ Vtg,
                                                      __hip_bfloat16* __restrict__ O) {
    __shared__ __hip_bfloat16 Ks[64 * 64];
    __shared__ __hip_bfloat16 Vs[64 * 64];
    __shared__ __hip_bfloat16 Ps[QBLK * 64];

    const int bid = blockIdx.x;
    const int swz = (bid & 7) * 64 + (bid >> 3);
    const int h = swz >> 4, qi = swz & 15;
    const int qb = qi * QBLK;
    const int kvh = h >> 2;

    const int t = threadIdx.x, w = t >> 6, l = t & 63;
    const int lr = l & 15, g = l >> 4, lk = g * 8;
    const int qbw = qb + 16 * w;      // this wave's 16 q-rows

    char* KsB = (char*)Ks;
    char* VsB = (char*)Vs;
    char* PsB = (char*)Ps;

    // hoisted Q fragments (one m-frag per wave)
    bx8 qa[2];
#pragma unroll
    for (int ks = 0; ks < 2; ks++)
        qa[ks] = *reinterpret_cast<const bx8*>(
            &Q[(size_t)(qbw + lr) * QKVN + h * HD + ks * 32 + lk]);

    fx4 o[4];
    float mrow[4], srow[4];
#pragma unroll
    for (int n = 0; n < 4; n++) o[n] = (fx4){0.f, 0.f, 0.f, 0.f};
#pragma unroll
    for (int r = 0; r < 4; r++) { mrow[r] = -1e30f; srow[r] = 0.f; }

    const int k0_first = (qb >= 1024) ? (qb - 1024) : 0;
    const int k0_last  = qb + 64;
    const int wmax = qbw + 15;

    // staging: 512 threads cover 64 rows x 8 us8-cols, one K + one V load each
    const int sr = t >> 3, sc8 = (t & 7) * 8;
    const int dst = sr * 128 + ((sc8 * 2) ^ ((sr & 7) << 4));

    for (int k0 = k0_first; k0 <= k0_last; k0 += 64) {
        us8 kv = *reinterpret_cast<const us8*>(&Kg[(size_t)(k0 + sr) * QKVN + kvh * HD + sc8]);
        us8 vv = *reinterpret_cast<const us8*>(&Vtg[(size_t)(kvh * HD + sr) * S_LEN + k0 + sc8]);
        *reinterpret_cast<us8*>(KsB + dst) = kv;
        *reinterpret_cast<us8*>(VsB + dst) = vv;
        __syncthreads();

        if (k0 <= wmax) {
            bx8 kb[4][2];
#pragma unroll
            for (int n = 0; n < 4; n++)
#pragma unroll
                for (int ks = 0; ks < 2; ks++) {
                    int row = 16 * n + lr;
                    kb[n][ks] = *reinterpret_cast<const bx8*>(
                        KsB + row * 128 + (((ks * 64) + 16 * g) ^ ((row & 7) << 4)));
                }
            fx4 sc[4];
#pragma unroll
            for (int n = 0; n < 4; n++) {
                sc[n] = __builtin_amdgcn_mfma_f32_16x16x32_bf16(qa[0], kb[n][0],
                                                                (fx4){0.f, 0.f, 0.f, 0.f}, 0, 0, 0);
                sc[n] = __builtin_amdgcn_mfma_f32_16x16x32_bf16(qa[1], kb[n][1], sc[n], 0, 0, 0);
            }
            // sliding-window mask (both edges) + scale
#pragma unroll
            for (int n = 0; n < 4; n++) {
                int col = k0 + 16 * n + lr;
#pragma unroll
                for (int r = 0; r < 4; r++) {
                    int rowq = qbw + 4 * g + r;
                    bool valid = (col <= rowq) && (col >= rowq - (WINDOW - 1));
                    sc[n][r] = valid ? sc[n][r] * 0.125f : -1e30f;
                }
            }
#pragma unroll
            for (int r = 0; r < 4; r++) {
                float tmax = fmaxf(fmaxf(sc[0][r], sc[1][r]), fmaxf(sc[2][r], sc[3][r]));
                tmax = fmaxf(tmax, __shfl_xor(tmax, 1));
                tmax = fmaxf(tmax, __shfl_xor(tmax, 2));
                tmax = fmaxf(tmax, __shfl_xor(tmax, 4));
                tmax = fmaxf(tmax, __shfl_xor(tmax, 8));
                float mo = mrow[r];
                float mn = fmaxf(mo, tmax);
                float fs = __expf(mo - mn);
                mrow[r] = mn;
                float ps = 0.f;
#pragma unroll
                for (int n = 0; n < 4; n++) {
                    float p = __expf(sc[n][r] - mn);
                    sc[n][r] = p;
                    ps += p;
                }
                ps += __shfl_xor(ps, 1);
                ps += __shfl_xor(ps, 2);
                ps += __shfl_xor(ps, 4);
                ps += __shfl_xor(ps, 8);
                srow[r] = srow[r] * fs + ps;
#pragma unroll
                for (int n = 0; n < 4; n++) o[n][r] *= fs;
            }
            // write P rows (wave-private rows [16w,16w+16))
#pragma unroll
            for (int r = 0; r < 4; r++) {
                int prow = 16 * w + 4 * g + r;
                char* pb = PsB + prow * 128;
                int sz = (prow & 7) << 4;
#pragma unroll
                for (int n = 0; n < 4; n++)
                    *reinterpret_cast<__hip_bfloat16*>(pb + (((16 * n + lr) * 2) ^ sz)) =
                        __float2bfloat16(sc[n][r]);
            }
            // V fragments + PV
            bx8 vb[4][2];
#pragma unroll
            for (int n = 0; n < 4; n++)
#pragma unroll
                for (int ks = 0; ks < 2; ks++) {
                    int row = 16 * n + lr;
                    vb[n][ks] = *reinterpret_cast<const bx8*>(
                        VsB + row * 128 + (((ks * 64) + 16 * g) ^ ((row & 7) << 4)));
                }
            bx8 pa[2];
#pragma unroll
            for (int ks = 0; ks < 2; ks++) {
                int prow = 16 * w + lr;
                pa[ks] = *reinterpret_cast<const bx8*>(
                    PsB + prow * 128 + (((ks * 64) + 16 * g) ^ ((prow & 7) << 4)));
            }
#pragma unroll
            for (int n = 0; n < 4; n++) {
                o[n] = __builtin_amdgcn_mfma_f32_16x16x32_bf16(pa[0], vb[n][0], o[n], 0, 0, 0);
                o[n] = __builtin_amdgcn_mfma_f32_16x16x32_bf16(pa[1], vb[n][1], o[n], 0, 0, 0);
            }
        }
        __syncthreads();
    }

    // ---- epilogue: normalize + store ----
    float inv[4];
#pragma unroll
    for (int r = 0; r < 4; r++) inv[r] = 1.f / srow[r];
#pragma unroll
    for (int n = 0; n < 4; n++)
#pragma unroll
        for (int r = 0; r < 4; r++) {
            int rq = qbw + 4 * g + r;
            O[(size_t)rq * HID + h * HD + 16 * n + lr] = __float2bfloat16(o[n][r] * inv[r]);
        }
}

extern "C" void kernel_launch(void* const* d_in, const int* in_sizes, int n_in,
                              void* d_out, int out_size, void* d_ws, size_t ws_size,
                              hipStream_t stream) {
    const float* hs = (const float*)d_in[0];
    const float* Wq = (const float*)d_in[1];
    const float* Wk = (const float*)d_in[2];
    const float* Wv = (const float*)d_in[3];
    const float* Wo = (const float*)d_in[4];

    float* ws   = (float*)d_ws;
    float* cosT = ws;                  // 65536 f32
    float* sinT = cosT + 65536;        // 65536 f32
    __hip_bfloat16* hsb    = (__hip_bfloat16*)(sinT + 65536);   // [2048][2048]
    __hip_bfloat16* WqkvT  = hsb + 4194304;                     // [3072][2048]: Wq|Wk|Wv rows
    __hip_bfloat16* WoT    = WqkvT + 6291456;                   // [2048][2048]
    __hip_bfloat16* QKVb   = WoT + 4194304;                     // [2048][3072]
    __hip_bfloat16* Vt     = QKVb + 6291456;                    // [512][2048]
    __hip_bfloat16* Ab     = hsb;                               // alias: hsb dead after QKV gemm

    rope_table_kernel<<<(S_LEN * 32) / 256, 256, 0, stream>>>(cosT, sinT);
    conv_kernel<<<2048, 256, 0, stream>>>(hs, hsb);
    convT_kernel<<<dim3(64, 64), dim3(32, 8), 0, stream>>>(Wq, WqkvT, 2048, 2048, 2048);
    convT_kernel<<<dim3(16, 64), dim3(32, 8), 0, stream>>>(Wk, WqkvT + (size_t)2048 * 2048, 2048, 512, 2048);
    convT_kernel<<<dim3(16, 64), dim3(32, 8), 0, stream>>>(Wv, WqkvT + (size_t)2560 * 2048, 2048, 512, 2048);
    convT_kernel<<<dim3(64, 64), dim3(32, 8), 0, stream>>>(Wo, WoT, 2048, 2048, 2048);

    // fused QKV projection: [2048][3072] = hsb @ WqkvT^T
    gemm_pipe_kernel<1><<<384, 256, 0, stream>>>(hsb, WqkvT, QKVb, 2048, QKVN, 2048, 24);

    // RoPE on Q and K (fused QKV layout)
    rope_kernel<<<(S_LEN * (NH + NKV) * 32) / 256, 256, 0, stream>>>(QKVb, cosT, sinT);

    vtrans_kernel<<<dim3(64, 16), dim3(32, 8), 0, stream>>>(QKVb, Vt);

    attn_kernel<<<512, 512, 0, stream>>>(QKVb, QKVb + 2048, Vt, Ab);

    // output projection: d_out = Ab @ WoT^T
    gemm_pipe_kernel<0><<<256, 256, 0, stream>>>(Ab, WoT, d_out, 2048, 2048, 2048, 16);
}

// Round 8
// 177.787 us; speedup vs baseline: 1.2839x; 1.0625x over previous
//
#include <hip/hip_runtime.h>
#include <hip/hip_bf16.h>
#include <math.h>

#define S_LEN 2048
#define HID 2048
#define NH 32
#define NKV 8
#define HD 64
#define WINDOW 1024
#define QBLK 128
#define QKVN 3072   // fused Q(2048) | K(512) | V(512) columns

typedef __attribute__((ext_vector_type(8))) short bx8;          // 8 bf16 (4 VGPRs) — MFMA A/B frag
typedef __attribute__((ext_vector_type(4))) float fx4;          // MFMA C/D frag
typedef __attribute__((ext_vector_type(8))) unsigned short us8; // 8 bf16 raw

#define GL_LDS16(gp, lp) \
    __builtin_amdgcn_global_load_lds((__attribute__((address_space(1))) const void*)(gp), \
                                     (__attribute__((address_space(3))) void*)(lp), 16, 0, 0)

// ---------------- RoPE tables (f64 on device, tiny) ----------------
__global__ void rope_table_kernel(float* __restrict__ cosT, float* __restrict__ sinT) {
    int idx = blockIdx.x * blockDim.x + threadIdx.x;  // s*32 + f
    if (idx >= S_LEN * 32) return;
    int s = idx >> 5, f = idx & 31;
    double inv = exp(-2.0 * (double)f / 64.0 * log(500000.0));
    double ang = (double)s * inv;
    cosT[idx] = (float)cos(ang);
    sinT[idx] = (float)sin(ang);
}

// ---------------- f32 -> bf16 elementwise ----------------
__global__ void conv_kernel(const float* __restrict__ in, __hip_bfloat16* __restrict__ out) {
    int i = (blockIdx.x * 256 + threadIdx.x) * 8;
    float4 a = *reinterpret_cast<const float4*>(&in[i]);
    float4 b = *reinterpret_cast<const float4*>(&in[i + 4]);
    __hip_bfloat16 o[8] __attribute__((aligned(16)));
    o[0] = __float2bfloat16(a.x); o[1] = __float2bfloat16(a.y);
    o[2] = __float2bfloat16(a.z); o[3] = __float2bfloat16(a.w);
    o[4] = __float2bfloat16(b.x); o[5] = __float2bfloat16(b.y);
    o[6] = __float2bfloat16(b.z); o[7] = __float2bfloat16(b.w);
    *reinterpret_cast<bx8*>(&out[i]) = *reinterpret_cast<bx8*>(o);
}

// ---------------- transpose+convert: out[n][k](bf16) = in[k][n](f32) ----------------
__global__ void convT_kernel(const float* __restrict__ in, __hip_bfloat16* __restrict__ out,
                             int K, int N, int outStride) {
    __shared__ float tile[32][33];
    int n0 = blockIdx.x * 32, k0 = blockIdx.y * 32;
    int tx = threadIdx.x, ty = threadIdx.y;  // 32 x 8
#pragma unroll
    for (int i = 0; i < 4; i++)
        tile[ty + 8 * i][tx] = in[(size_t)(k0 + ty + 8 * i) * N + n0 + tx];
    __syncthreads();
#pragma unroll
    for (int i = 0; i < 4; i++)
        out[(size_t)(n0 + ty + 8 * i) * outStride + k0 + tx] = __float2bfloat16(tile[tx][ty + 8 * i]);
}

// ---------------- bf16 transpose: Vt[d][s] = QKV[s][2560+d] ----------------
__global__ void vtrans_kernel(const __hip_bfloat16* __restrict__ QKV, __hip_bfloat16* __restrict__ Vt) {
    __shared__ __hip_bfloat16 tile[32][33];
    int s0 = blockIdx.x * 32, d0 = blockIdx.y * 32;
    int tx = threadIdx.x, ty = threadIdx.y;  // 32 x 8
#pragma unroll
    for (int i = 0; i < 4; i++)
        tile[ty + 8 * i][tx] = QKV[(size_t)(s0 + ty + 8 * i) * QKVN + 2560 + d0 + tx];
    __syncthreads();
#pragma unroll
    for (int i = 0; i < 4; i++)
        Vt[(size_t)(d0 + ty + 8 * i) * S_LEN + s0 + tx] = tile[tx][ty + 8 * i];
}

// ---------------- bf16 transpose: Ab[s][hid] = Ot[hid][s] ----------------
__global__ void otrans_kernel(const __hip_bfloat16* __restrict__ Ot, __hip_bfloat16* __restrict__ Ab) {
    __shared__ __hip_bfloat16 tile[32][33];
    int h0 = blockIdx.x * 32, s0 = blockIdx.y * 32;
    int tx = threadIdx.x, ty = threadIdx.y;  // 32 x 8
#pragma unroll
    for (int i = 0; i < 4; i++)
        tile[ty + 8 * i][tx] = Ot[(size_t)(h0 + ty + 8 * i) * S_LEN + s0 + tx];
    __syncthreads();
#pragma unroll
    for (int i = 0; i < 4; i++)
        Ab[(size_t)(s0 + ty + 8 * i) * HID + h0 + tx] = tile[tx][ty + 8 * i];
}

// ---------------- pipelined bf16 MFMA GEMM (frozen from R5) ----------------
template <int OUTBF16>
__global__ __launch_bounds__(256) void gemm_pipe_kernel(const __hip_bfloat16* __restrict__ A,
                                                        const __hip_bfloat16* __restrict__ Bt,
                                                        void* __restrict__ Cp,
                                                        int M, int N, int K, int nbx) {
    __shared__ __hip_bfloat16 As[3][4096];
    __shared__ __hip_bfloat16 Bs[3][4096];

    const int nwg = gridDim.x, cpx = nwg >> 3, bid = blockIdx.x;
    const int swz = (bid & 7) * cpx + (bid >> 3);
    const int bm = (swz / nbx) * 128, bn = (swz % nbx) * 128;

    const int t = threadIdx.x, w = t >> 6, l = t & 63;
    const int wr = (w >> 1) * 64, wc = (w & 1) * 64;
    const int lr = l & 15, lk = (l >> 4) * 8;
    const int srow = w * 16 + (l >> 2);
    const int scol = (l & 3) * 8;
    const int ldsoff = w * 512;

    const __hip_bfloat16* ga0 = A + (size_t)(bm + srow) * K + scol;
    const __hip_bfloat16* gb0 = Bt + (size_t)(bn + srow) * K + scol;
    const size_t half = (size_t)64 * K;

    fx4 acc[4][4];
#pragma unroll
    for (int m = 0; m < 4; m++)
#pragma unroll
        for (int n = 0; n < 4; n++) acc[m][n] = (fx4){0.f, 0.f, 0.f, 0.f};

    const int T = K >> 5;

#define STAGE(kt, b)                                              \
    do {                                                          \
        const __hip_bfloat16* ga = ga0 + (kt) * 32;               \
        const __hip_bfloat16* gb = gb0 + (kt) * 32;               \
        GL_LDS16(ga,        &As[(b)][ldsoff]);                    \
        GL_LDS16(ga + half, &As[(b)][2048 + ldsoff]);             \
        GL_LDS16(gb,        &Bs[(b)][ldsoff]);                    \
        GL_LDS16(gb + half, &Bs[(b)][2048 + ldsoff]);             \
    } while (0)

    STAGE(0, 0);
    STAGE(1, 1);

    for (int i = 0; i < T; i++) {
        const int r = i % 3;
        if (i + 1 < T) asm volatile("s_waitcnt vmcnt(4)" ::: "memory");
        else           asm volatile("s_waitcnt vmcnt(0)" ::: "memory");
        __builtin_amdgcn_s_barrier();
        asm volatile("" ::: "memory");
        if (i + 2 < T) STAGE(i + 2, (i + 2) % 3);

        bx8 af[4], bf[4];
#pragma unroll
        for (int m = 0; m < 4; m++)
            af[m] = *reinterpret_cast<const bx8*>(&As[r][(wr + m * 16 + lr) * 32 + lk]);
#pragma unroll
        for (int n = 0; n < 4; n++)
            bf[n] = *reinterpret_cast<const bx8*>(&Bs[r][(wc + n * 16 + lr) * 32 + lk]);
#pragma unroll
        for (int m = 0; m < 4; m++)
#pragma unroll
            for (int n = 0; n < 4; n++)
                acc[m][n] = __builtin_amdgcn_mfma_f32_16x16x32_bf16(af[m], bf[n], acc[m][n], 0, 0, 0);
    }
#undef STAGE

    const int lq = (l >> 4) * 4;
#pragma unroll
    for (int m = 0; m < 4; m++)
#pragma unroll
        for (int n = 0; n < 4; n++)
#pragma unroll
            for (int r2 = 0; r2 < 4; r2++) {
                int row = bm + wr + m * 16 + lq + r2;
                int col = bn + wc + n * 16 + lr;
                float v = acc[m][n][r2];
                if (OUTBF16)
                    ((__hip_bfloat16*)Cp)[(size_t)row * N + col] = __float2bfloat16(v);
                else
                    ((float*)Cp)[(size_t)row * N + col] = v;
            }
}

// ---------------- RoPE in-place on fused QKV [S][3072] (Q cols 0-2047, K cols 2048-2559) ----------------
__global__ void rope_kernel(__hip_bfloat16* __restrict__ QKV,
                            const float* __restrict__ cosT, const float* __restrict__ sinT) {
    int idx = blockIdx.x * blockDim.x + threadIdx.x;  // s*(40*32) + head*32 + f
    int f = idx & 31;
    int head = (idx >> 5) % (NH + NKV);
    int s = idx / ((NH + NKV) * 32);
    if (s >= S_LEN) return;
    float c  = cosT[(s << 5) + f];
    float sn = sinT[(s << 5) + f];
    __hip_bfloat16* p = (head < NH) ? (QKV + (size_t)s * QKVN + head * HD)
                                    : (QKV + (size_t)s * QKVN + 2048 + (head - NH) * HD);
    float x1 = __bfloat162float(p[f]), x2 = __bfloat162float(p[f + 32]);
    p[f]      = __float2bfloat16(x1 * c - x2 * sn);
    p[f + 32] = __float2bfloat16(x2 * c + x1 * sn);
}

// ---------------- MFMA sliding-window flash attention, swapped-operand softmax ----------------
// R8: S^T = mfma(K,Q) so each lane owns one q-row (q=lane&15) -> in-register
// row-reduce + 2 shfl_xor. PV swapped too: O^T = mfma(Vt, P), one fs/inv per lane.
// Output written transposed to Ot[hid][s]; otrans restores.
__global__ __launch_bounds__(512, 4) void attn_kernel(const __hip_bfloat16* __restrict__ Q,
                                                      const __hip_bfloat16* __restrict__ Kg,
                                                      const __hip_bfloat16* __restrict__ Vtg,
                                                      __hip_bfloat16* __restrict__ Ot) {
    __shared__ __hip_bfloat16 Ks[64 * 64];
    __shared__ __hip_bfloat16 Vs[64 * 64];
    __shared__ __hip_bfloat16 Ps[QBLK * 64];

    const int bid = blockIdx.x;
    const int swz = (bid & 7) * 64 + (bid >> 3);
    const int h = swz >> 4, qi = swz & 15;
    const int qb = qi * QBLK;
    const int kvh = h >> 2;

    const int t = threadIdx.x, w = t >> 6, l = t & 63;
    const int lr = l & 15, g = l >> 4, lk = g * 8;
    const int qbw = qb + 16 * w;      // this wave's 16 q-rows
    const int prow = 16 * w + lr;     // this lane's q-row in Ps
    const int psz = (prow & 7) << 4;

    char* KsB = (char*)Ks;
    char* VsB = (char*)Vs;
    char* PsB = (char*)Ps;

    // hoisted Q fragments (B-operand; lane holds q-row lr)
    bx8 qa[2];
#pragma unroll
    for (int ks = 0; ks < 2; ks++)
        qa[ks] = *reinterpret_cast<const bx8*>(
            &Q[(size_t)(qbw + lr) * QKVN + h * HD + ks * 32 + lk]);

    fx4 ot[4];
#pragma unroll
    for (int n = 0; n < 4; n++) ot[n] = (fx4){0.f, 0.f, 0.f, 0.f};
    float mrow = -1e30f, srow = 0.f;

    const int k0_first = (qb >= 1024) ? (qb - 1024) : 0;
    const int k0_last  = qb + 64;
    const int wmax = qbw + 15;
    const int rowq = qbw + lr;        // this lane's q-row (global)

    // staging: 512 threads cover 64 rows x 8 us8-cols, one K + one V load each
    const int sr = t >> 3, sc8 = (t & 7) * 8;
    const int dst = sr * 128 + ((sc8 * 2) ^ ((sr & 7) << 4));

    for (int k0 = k0_first; k0 <= k0_last; k0 += 64) {
        us8 kv = *reinterpret_cast<const us8*>(&Kg[(size_t)(k0 + sr) * QKVN + kvh * HD + sc8]);
        us8 vv = *reinterpret_cast<const us8*>(&Vtg[(size_t)(kvh * HD + sr) * S_LEN + k0 + sc8]);
        *reinterpret_cast<us8*>(KsB + dst) = kv;
        *reinterpret_cast<us8*>(VsB + dst) = vv;
        __syncthreads();

        if (k0 <= wmax) {
            // K fragments (A-operand: rows = keys)
            bx8 kb[4][2];
#pragma unroll
            for (int n = 0; n < 4; n++)
#pragma unroll
                for (int ks = 0; ks < 2; ks++) {
                    int row = 16 * n + lr;
                    kb[n][ks] = *reinterpret_cast<const bx8*>(
                        KsB + row * 128 + (((ks * 64) + 16 * g) ^ ((row & 7) << 4)));
                }
            // S^T = K · Q^T : rows=keys (16n+4g+r), cols=q (lr)
            fx4 sc[4];
#pragma unroll
            for (int n = 0; n < 4; n++) {
                sc[n] = __builtin_amdgcn_mfma_f32_16x16x32_bf16(kb[n][0], qa[0],
                                                                (fx4){0.f, 0.f, 0.f, 0.f}, 0, 0, 0);
                sc[n] = __builtin_amdgcn_mfma_f32_16x16x32_bf16(kb[n][1], qa[1], sc[n], 0, 0, 0);
            }
            // scale + sliding-window mask (interior tiles skip the mask)
            const bool interior = (k0 + 63 <= qbw) && (k0 >= qbw - 1008);
            if (interior) {
#pragma unroll
                for (int n = 0; n < 4; n++)
#pragma unroll
                    for (int r = 0; r < 4; r++) sc[n][r] *= 0.125f;
            } else {
#pragma unroll
                for (int n = 0; n < 4; n++)
#pragma unroll
                    for (int r = 0; r < 4; r++) {
                        int key = k0 + 16 * n + 4 * g + r;
                        bool valid = (key <= rowq) && (key >= rowq - (WINDOW - 1));
                        sc[n][r] = valid ? sc[n][r] * 0.125f : -1e30f;
                    }
            }
            // in-register row max (lane owns its whole 64-key slice split over 4 groups)
            float tmax = fmaxf(fmaxf(sc[0][0], sc[0][1]), fmaxf(sc[0][2], sc[0][3]));
#pragma unroll
            for (int n = 1; n < 4; n++)
                tmax = fmaxf(tmax, fmaxf(fmaxf(sc[n][0], sc[n][1]), fmaxf(sc[n][2], sc[n][3])));
            tmax = fmaxf(tmax, __shfl_xor(tmax, 16));
            tmax = fmaxf(tmax, __shfl_xor(tmax, 32));
            float mn = fmaxf(mrow, tmax);
            float fs = __expf(mrow - mn);
            mrow = mn;
            // exp + P^T write (packed b64, lane's own row) + sum
            float ps = 0.f;
#pragma unroll
            for (int n = 0; n < 4; n++) {
#pragma unroll
                for (int r = 0; r < 4; r++) {
                    float p = __expf(sc[n][r] - mn);
                    sc[n][r] = p;
                    ps += p;
                }
                __hip_bfloat16 pk[4] __attribute__((aligned(8)));
                pk[0] = __float2bfloat16(sc[n][0]); pk[1] = __float2bfloat16(sc[n][1]);
                pk[2] = __float2bfloat16(sc[n][2]); pk[3] = __float2bfloat16(sc[n][3]);
                *reinterpret_cast<unsigned long long*>(PsB + prow * 128 + ((32 * n + 8 * g) ^ psz)) =
                    *reinterpret_cast<unsigned long long*>(pk);
            }
            ps += __shfl_xor(ps, 16);
            ps += __shfl_xor(ps, 32);
            srow = srow * fs + ps;
#pragma unroll
            for (int n = 0; n < 4; n++)
#pragma unroll
                for (int r = 0; r < 4; r++) ot[n][r] *= fs;
            // V fragments (A-operand: rows = d) + P fragments (B-operand: rows = q)
            bx8 vb[4][2];
#pragma unroll
            for (int n = 0; n < 4; n++)
#pragma unroll
                for (int ks = 0; ks < 2; ks++) {
                    int row = 16 * n + lr;
                    vb[n][ks] = *reinterpret_cast<const bx8*>(
                        VsB + row * 128 + (((ks * 64) + 16 * g) ^ ((row & 7) << 4)));
                }
            bx8 pb[2];
#pragma unroll
            for (int ks = 0; ks < 2; ks++)
                pb[ks] = *reinterpret_cast<const bx8*>(
                    PsB + prow * 128 + (((ks * 64) + 16 * g) ^ psz));
            // O^T += V^T · P : rows=d (16n+4g+r), cols=q (lr)
#pragma unroll
            for (int n = 0; n < 4; n++) {
                ot[n] = __builtin_amdgcn_mfma_f32_16x16x32_bf16(vb[n][0], pb[0], ot[n], 0, 0, 0);
                ot[n] = __builtin_amdgcn_mfma_f32_16x16x32_bf16(vb[n][1], pb[1], ot[n], 0, 0, 0);
            }
        }
        __syncthreads();
    }

    // ---- epilogue: normalize (one inv per lane) + store O^T ----
    const float inv = 1.f / srow;
#pragma unroll
    for (int n = 0; n < 4; n++)
#pragma unroll
        for (int r = 0; r < 4; r++) {
            int d = h * HD + 16 * n + 4 * g + r;
            Ot[(size_t)d * S_LEN + qbw + lr] = __float2bfloat16(ot[n][r] * inv);
        }
}

extern "C" void kernel_launch(void* const* d_in, const int* in_sizes, int n_in,
                              void* d_out, int out_size, void* d_ws, size_t ws_size,
                              hipStream_t stream) {
    const float* hs = (const float*)d_in[0];
    const float* Wq = (const float*)d_in[1];
    const float* Wk = (const float*)d_in[2];
    const float* Wv = (const float*)d_in[3];
    const float* Wo = (const float*)d_in[4];

    float* ws   = (float*)d_ws;
    float* cosT = ws;                  // 65536 f32
    float* sinT = cosT + 65536;        // 65536 f32
    __hip_bfloat16* hsb    = (__hip_bfloat16*)(sinT + 65536);   // [2048][2048]
    __hip_bfloat16* WqkvT  = hsb + 4194304;                     // [3072][2048]: Wq|Wk|Wv rows
    __hip_bfloat16* WoT    = WqkvT + 6291456;                   // [2048][2048]
    __hip_bfloat16* QKVb   = WoT + 4194304;                     // [2048][3072]
    __hip_bfloat16* Vt     = QKVb + 6291456;                    // [512][2048]
    __hip_bfloat16* Ot     = WqkvT;                             // alias: WqkvT dead after QKV gemm; [2048][2048] O^T
    __hip_bfloat16* Ab     = hsb;                               // alias: hsb dead after QKV gemm

    rope_table_kernel<<<(S_LEN * 32) / 256, 256, 0, stream>>>(cosT, sinT);
    conv_kernel<<<2048, 256, 0, stream>>>(hs, hsb);
    convT_kernel<<<dim3(64, 64), dim3(32, 8), 0, stream>>>(Wq, WqkvT, 2048, 2048, 2048);
    convT_kernel<<<dim3(16, 64), dim3(32, 8), 0, stream>>>(Wk, WqkvT + (size_t)2048 * 2048, 2048, 512, 2048);
    convT_kernel<<<dim3(16, 64), dim3(32, 8), 0, stream>>>(Wv, WqkvT + (size_t)2560 * 2048, 2048, 512, 2048);
    convT_kernel<<<dim3(64, 64), dim3(32, 8), 0, stream>>>(Wo, WoT, 2048, 2048, 2048);

    // fused QKV projection: [2048][3072] = hsb @ WqkvT^T
    gemm_pipe_kernel<1><<<384, 256, 0, stream>>>(hsb, WqkvT, QKVb, 2048, QKVN, 2048, 24);

    // RoPE on Q and K (fused QKV layout)
    rope_kernel<<<(S_LEN * (NH + NKV) * 32) / 256, 256, 0, stream>>>(QKVb, cosT, sinT);

    vtrans_kernel<<<dim3(64, 16), dim3(32, 8), 0, stream>>>(QKVb, Vt);

    attn_kernel<<<512, 512, 0, stream>>>(QKVb, QKVb + 2048, Vt, Ot);

    // restore row-major O for the Wo gemm
    otrans_kernel<<<dim3(64, 64), dim3(32, 8), 0, stream>>>(Ot, Ab);

    // output projection: d_out = Ab @ WoT^T
    gemm_pipe_kernel<0><<<256, 256, 0, stream>>>(Ab, WoT, d_out, 2048, 2048, 2048, 16);
}

// Round 9
// 173.735 us; speedup vs baseline: 1.3138x; 1.0233x over previous
//
#include <hip/hip_runtime.h>
#include <hip/hip_bf16.h>
#include <math.h>

#define S_LEN 2048
#define HID 2048
#define NH 32
#define NKV 8
#define HD 64
#define WINDOW 1024
#define QBLK 128
#define QKVN 3072   // fused Q(2048) | K(512) | V(512) columns

typedef __attribute__((ext_vector_type(8))) short bx8;          // 8 bf16 (4 VGPRs) — MFMA A/B frag
typedef __attribute__((ext_vector_type(4))) float fx4;          // MFMA C/D frag
typedef __attribute__((ext_vector_type(8))) unsigned short us8; // 8 bf16 raw

#define GL_LDS16(gp, lp) \
    __builtin_amdgcn_global_load_lds((__attribute__((address_space(1))) const void*)(gp), \
                                     (__attribute__((address_space(3))) void*)(lp), 16, 0, 0)

// ---------------- RoPE tables (f64 on device, tiny) ----------------
__global__ void rope_table_kernel(float* __restrict__ cosT, float* __restrict__ sinT) {
    int idx = blockIdx.x * blockDim.x + threadIdx.x;  // s*32 + f
    if (idx >= S_LEN * 32) return;
    int s = idx >> 5, f = idx & 31;
    double inv = exp(-2.0 * (double)f / 64.0 * log(500000.0));
    double ang = (double)s * inv;
    cosT[idx] = (float)cos(ang);
    sinT[idx] = (float)sin(ang);
}

// ---------------- f32 -> bf16 elementwise ----------------
__global__ void conv_kernel(const float* __restrict__ in, __hip_bfloat16* __restrict__ out) {
    int i = (blockIdx.x * 256 + threadIdx.x) * 8;
    float4 a = *reinterpret_cast<const float4*>(&in[i]);
    float4 b = *reinterpret_cast<const float4*>(&in[i + 4]);
    __hip_bfloat16 o[8] __attribute__((aligned(16)));
    o[0] = __float2bfloat16(a.x); o[1] = __float2bfloat16(a.y);
    o[2] = __float2bfloat16(a.z); o[3] = __float2bfloat16(a.w);
    o[4] = __float2bfloat16(b.x); o[5] = __float2bfloat16(b.y);
    o[6] = __float2bfloat16(b.z); o[7] = __float2bfloat16(b.w);
    *reinterpret_cast<bx8*>(&out[i]) = *reinterpret_cast<bx8*>(o);
}

// ---------------- transpose+convert: out[n][k](bf16) = in[k][n](f32) ----------------
__global__ void convT_kernel(const float* __restrict__ in, __hip_bfloat16* __restrict__ out,
                             int K, int N, int outStride) {
    __shared__ float tile[32][33];
    int n0 = blockIdx.x * 32, k0 = blockIdx.y * 32;
    int tx = threadIdx.x, ty = threadIdx.y;  // 32 x 8
#pragma unroll
    for (int i = 0; i < 4; i++)
        tile[ty + 8 * i][tx] = in[(size_t)(k0 + ty + 8 * i) * N + n0 + tx];
    __syncthreads();
#pragma unroll
    for (int i = 0; i < 4; i++)
        out[(size_t)(n0 + ty + 8 * i) * outStride + k0 + tx] = __float2bfloat16(tile[tx][ty + 8 * i]);
}

// ---------------- bf16 transpose: Vt[d][s] = QKV[s][2560+d] ----------------
__global__ void vtrans_kernel(const __hip_bfloat16* __restrict__ QKV, __hip_bfloat16* __restrict__ Vt) {
    __shared__ __hip_bfloat16 tile[32][33];
    int s0 = blockIdx.x * 32, d0 = blockIdx.y * 32;
    int tx = threadIdx.x, ty = threadIdx.y;  // 32 x 8
#pragma unroll
    for (int i = 0; i < 4; i++)
        tile[ty + 8 * i][tx] = QKV[(size_t)(s0 + ty + 8 * i) * QKVN + 2560 + d0 + tx];
    __syncthreads();
#pragma unroll
    for (int i = 0; i < 4; i++)
        Vt[(size_t)(d0 + ty + 8 * i) * S_LEN + s0 + tx] = tile[tx][ty + 8 * i];
}

// ---------------- bf16 transpose: Ab[s][hid] = Ot[hid][s] ----------------
__global__ void otrans_kernel(const __hip_bfloat16* __restrict__ Ot, __hip_bfloat16* __restrict__ Ab) {
    __shared__ __hip_bfloat16 tile[32][33];
    int h0 = blockIdx.x * 32, s0 = blockIdx.y * 32;
    int tx = threadIdx.x, ty = threadIdx.y;  // 32 x 8
#pragma unroll
    for (int i = 0; i < 4; i++)
        tile[ty + 8 * i][tx] = Ot[(size_t)(h0 + ty + 8 * i) * S_LEN + s0 + tx];
    __syncthreads();
#pragma unroll
    for (int i = 0; i < 4; i++)
        Ab[(size_t)(s0 + ty + 8 * i) * HID + h0 + tx] = tile[tx][ty + 8 * i];
}

// ---------------- pipelined bf16 MFMA GEMM with LDS bank swizzle ----------------
// R9: slot(row) ^= (row>>1)&3 — even rows spread over bank-quads 0-3, odd rows
// 4-7, exactly 2 rows/quad per 16-lane group => 2-way (free). Write side keeps
// global_load_lds dest linear; the GLOBAL source slot is pre-swizzled (rule 21).
template <int OUTBF16>
__global__ __launch_bounds__(256) void gemm_pipe_kernel(const __hip_bfloat16* __restrict__ A,
                                                        const __hip_bfloat16* __restrict__ Bt,
                                                        void* __restrict__ Cp,
                                                        int M, int N, int K, int nbx) {
    __shared__ __hip_bfloat16 As[3][4096];
    __shared__ __hip_bfloat16 Bs[3][4096];

    const int nwg = gridDim.x, cpx = nwg >> 3, bid = blockIdx.x;
    const int swz = (bid & 7) * cpx + (bid >> 3);
    const int bm = (swz / nbx) * 128, bn = (swz % nbx) * 128;

    const int t = threadIdx.x, w = t >> 6, l = t & 63;
    const int wr = (w >> 1) * 64, wc = (w & 1) * 64;
    const int lr = l & 15;
    // swizzled read slot: g ^ ((row>>1)&3), lane-uniform across m/n since wr+m*16 % 16 == 0
    const int rdslot = (((l >> 4) ^ ((lr >> 1) & 3))) * 8;
    const int srow = w * 16 + (l >> 2);
    // pre-swizzled global source slot for the linear LDS write
    const int scol = (((l & 3) ^ ((l >> 3) & 3))) * 8;
    const int ldsoff = w * 512;

    const __hip_bfloat16* ga0 = A + (size_t)(bm + srow) * K + scol;
    const __hip_bfloat16* gb0 = Bt + (size_t)(bn + srow) * K + scol;
    const size_t half = (size_t)64 * K;

    fx4 acc[4][4];
#pragma unroll
    for (int m = 0; m < 4; m++)
#pragma unroll
        for (int n = 0; n < 4; n++) acc[m][n] = (fx4){0.f, 0.f, 0.f, 0.f};

    const int T = K >> 5;

#define STAGE(kt, b)                                              \
    do {                                                          \
        const __hip_bfloat16* ga = ga0 + (kt) * 32;               \
        const __hip_bfloat16* gb = gb0 + (kt) * 32;               \
        GL_LDS16(ga,        &As[(b)][ldsoff]);                    \
        GL_LDS16(ga + half, &As[(b)][2048 + ldsoff]);             \
        GL_LDS16(gb,        &Bs[(b)][ldsoff]);                    \
        GL_LDS16(gb + half, &Bs[(b)][2048 + ldsoff]);             \
    } while (0)

    STAGE(0, 0);
    STAGE(1, 1);

    for (int i = 0; i < T; i++) {
        const int r = i % 3;
        if (i + 1 < T) asm volatile("s_waitcnt vmcnt(4)" ::: "memory");
        else           asm volatile("s_waitcnt vmcnt(0)" ::: "memory");
        __builtin_amdgcn_s_barrier();
        asm volatile("" ::: "memory");
        if (i + 2 < T) STAGE(i + 2, (i + 2) % 3);

        bx8 af[4], bf[4];
#pragma unroll
        for (int m = 0; m < 4; m++)
            af[m] = *reinterpret_cast<const bx8*>(&As[r][(wr + m * 16 + lr) * 32 + rdslot]);
#pragma unroll
        for (int n = 0; n < 4; n++)
            bf[n] = *reinterpret_cast<const bx8*>(&Bs[r][(wc + n * 16 + lr) * 32 + rdslot]);
#pragma unroll
        for (int m = 0; m < 4; m++)
#pragma unroll
            for (int n = 0; n < 4; n++)
                acc[m][n] = __builtin_amdgcn_mfma_f32_16x16x32_bf16(af[m], bf[n], acc[m][n], 0, 0, 0);
    }
#undef STAGE

    const int lq = (l >> 4) * 4;
#pragma unroll
    for (int m = 0; m < 4; m++)
#pragma unroll
        for (int n = 0; n < 4; n++)
#pragma unroll
            for (int r2 = 0; r2 < 4; r2++) {
                int row = bm + wr + m * 16 + lq + r2;
                int col = bn + wc + n * 16 + lr;
                float v = acc[m][n][r2];
                if (OUTBF16)
                    ((__hip_bfloat16*)Cp)[(size_t)row * N + col] = __float2bfloat16(v);
                else
                    ((float*)Cp)[(size_t)row * N + col] = v;
            }
}

// ---------------- RoPE in-place on fused QKV [S][3072] (Q cols 0-2047, K cols 2048-2559) ----------------
__global__ void rope_kernel(__hip_bfloat16* __restrict__ QKV,
                            const float* __restrict__ cosT, const float* __restrict__ sinT) {
    int idx = blockIdx.x * blockDim.x + threadIdx.x;  // s*(40*32) + head*32 + f
    int f = idx & 31;
    int head = (idx >> 5) % (NH + NKV);
    int s = idx / ((NH + NKV) * 32);
    if (s >= S_LEN) return;
    float c  = cosT[(s << 5) + f];
    float sn = sinT[(s << 5) + f];
    __hip_bfloat16* p = (head < NH) ? (QKV + (size_t)s * QKVN + head * HD)
                                    : (QKV + (size_t)s * QKVN + 2048 + (head - NH) * HD);
    float x1 = __bfloat162float(p[f]), x2 = __bfloat162float(p[f + 32]);
    p[f]      = __float2bfloat16(x1 * c - x2 * sn);
    p[f + 32] = __float2bfloat16(x2 * c + x1 * sn);
}

// ---------------- MFMA sliding-window flash attention, swapped-operand softmax (frozen R8) ----------------
__global__ __launch_bounds__(512, 4) void attn_kernel(const __hip_bfloat16* __restrict__ Q,
                                                      const __hip_bfloat16* __restrict__ Kg,
                                                      const __hip_bfloat16* __restrict__ Vtg,
                                                      __hip_bfloat16* __restrict__ Ot) {
    __shared__ __hip_bfloat16 Ks[64 * 64];
    __shared__ __hip_bfloat16 Vs[64 * 64];
    __shared__ __hip_bfloat16 Ps[QBLK * 64];

    const int bid = blockIdx.x;
    const int swz = (bid & 7) * 64 + (bid >> 3);
    const int h = swz >> 4, qi = swz & 15;
    const int qb = qi * QBLK;
    const int kvh = h >> 2;

    const int t = threadIdx.x, w = t >> 6, l = t & 63;
    const int lr = l & 15, g = l >> 4, lk = g * 8;
    const int qbw = qb + 16 * w;      // this wave's 16 q-rows
    const int prow = 16 * w + lr;     // this lane's q-row in Ps
    const int psz = (prow & 7) << 4;

    char* KsB = (char*)Ks;
    char* VsB = (char*)Vs;
    char* PsB = (char*)Ps;

    // hoisted Q fragments (B-operand; lane holds q-row lr)
    bx8 qa[2];
#pragma unroll
    for (int ks = 0; ks < 2; ks++)
        qa[ks] = *reinterpret_cast<const bx8*>(
            &Q[(size_t)(qbw + lr) * QKVN + h * HD + ks * 32 + lk]);

    fx4 ot[4];
#pragma unroll
    for (int n = 0; n < 4; n++) ot[n] = (fx4){0.f, 0.f, 0.f, 0.f};
    float mrow = -1e30f, srow = 0.f;

    const int k0_first = (qb >= 1024) ? (qb - 1024) : 0;
    const int k0_last  = qb + 64;
    const int wmax = qbw + 15;
    const int rowq = qbw + lr;        // this lane's q-row (global)

    // staging: 512 threads cover 64 rows x 8 us8-cols, one K + one V load each
    const int sr = t >> 3, sc8 = (t & 7) * 8;
    const int dst = sr * 128 + ((sc8 * 2) ^ ((sr & 7) << 4));

    for (int k0 = k0_first; k0 <= k0_last; k0 += 64) {
        us8 kv = *reinterpret_cast<const us8*>(&Kg[(size_t)(k0 + sr) * QKVN + kvh * HD + sc8]);
        us8 vv = *reinterpret_cast<const us8*>(&Vtg[(size_t)(kvh * HD + sr) * S_LEN + k0 + sc8]);
        *reinterpret_cast<us8*>(KsB + dst) = kv;
        *reinterpret_cast<us8*>(VsB + dst) = vv;
        __syncthreads();

        if (k0 <= wmax) {
            // K fragments (A-operand: rows = keys)
            bx8 kb[4][2];
#pragma unroll
            for (int n = 0; n < 4; n++)
#pragma unroll
                for (int ks = 0; ks < 2; ks++) {
                    int row = 16 * n + lr;
                    kb[n][ks] = *reinterpret_cast<const bx8*>(
                        KsB + row * 128 + (((ks * 64) + 16 * g) ^ ((row & 7) << 4)));
                }
            // S^T = K · Q^T : rows=keys (16n+4g+r), cols=q (lr)
            fx4 sc[4];
#pragma unroll
            for (int n = 0; n < 4; n++) {
                sc[n] = __builtin_amdgcn_mfma_f32_16x16x32_bf16(kb[n][0], qa[0],
                                                                (fx4){0.f, 0.f, 0.f, 0.f}, 0, 0, 0);
                sc[n] = __builtin_amdgcn_mfma_f32_16x16x32_bf16(kb[n][1], qa[1], sc[n], 0, 0, 0);
            }
            // scale + sliding-window mask (interior tiles skip the mask)
            const bool interior = (k0 + 63 <= qbw) && (k0 >= qbw - 1008);
            if (interior) {
#pragma unroll
                for (int n = 0; n < 4; n++)
#pragma unroll
                    for (int r = 0; r < 4; r++) sc[n][r] *= 0.125f;
            } else {
#pragma unroll
                for (int n = 0; n < 4; n++)
#pragma unroll
                    for (int r = 0; r < 4; r++) {
                        int key = k0 + 16 * n + 4 * g + r;
                        bool valid = (key <= rowq) && (key >= rowq - (WINDOW - 1));
                        sc[n][r] = valid ? sc[n][r] * 0.125f : -1e30f;
                    }
            }
            // in-register row max
            float tmax = fmaxf(fmaxf(sc[0][0], sc[0][1]), fmaxf(sc[0][2], sc[0][3]));
#pragma unroll
            for (int n = 1; n < 4; n++)
                tmax = fmaxf(tmax, fmaxf(fmaxf(sc[n][0], sc[n][1]), fmaxf(sc[n][2], sc[n][3])));
            tmax = fmaxf(tmax, __shfl_xor(tmax, 16));
            tmax = fmaxf(tmax, __shfl_xor(tmax, 32));
            float mn = fmaxf(mrow, tmax);
            float fs = __expf(mrow - mn);
            mrow = mn;
            // exp + P^T write (packed b64, lane's own row) + sum
            float ps = 0.f;
#pragma unroll
            for (int n = 0; n < 4; n++) {
#pragma unroll
                for (int r = 0; r < 4; r++) {
                    float p = __expf(sc[n][r] - mn);
                    sc[n][r] = p;
                    ps += p;
                }
                __hip_bfloat16 pk[4] __attribute__((aligned(8)));
                pk[0] = __float2bfloat16(sc[n][0]); pk[1] = __float2bfloat16(sc[n][1]);
                pk[2] = __float2bfloat16(sc[n][2]); pk[3] = __float2bfloat16(sc[n][3]);
                *reinterpret_cast<unsigned long long*>(PsB + prow * 128 + ((32 * n + 8 * g) ^ psz)) =
                    *reinterpret_cast<unsigned long long*>(pk);
            }
            ps += __shfl_xor(ps, 16);
            ps += __shfl_xor(ps, 32);
            srow = srow * fs + ps;
#pragma unroll
            for (int n = 0; n < 4; n++)
#pragma unroll
                for (int r = 0; r < 4; r++) ot[n][r] *= fs;
            // V fragments (A-operand: rows = d) + P fragments (B-operand: rows = q)
            bx8 vb[4][2];
#pragma unroll
            for (int n = 0; n < 4; n++)
#pragma unroll
                for (int ks = 0; ks < 2; ks++) {
                    int row = 16 * n + lr;
                    vb[n][ks] = *reinterpret_cast<const bx8*>(
                        VsB + row * 128 + (((ks * 64) + 16 * g) ^ ((row & 7) << 4)));
                }
            bx8 pb[2];
#pragma unroll
            for (int ks = 0; ks < 2; ks++)
                pb[ks] = *reinterpret_cast<const bx8*>(
                    PsB + prow * 128 + (((ks * 64) + 16 * g) ^ psz));
            // O^T += V^T · P : rows=d (16n+4g+r), cols=q (lr)
#pragma unroll
            for (int n = 0; n < 4; n++) {
                ot[n] = __builtin_amdgcn_mfma_f32_16x16x32_bf16(vb[n][0], pb[0], ot[n], 0, 0, 0);
                ot[n] = __builtin_amdgcn_mfma_f32_16x16x32_bf16(vb[n][1], pb[1], ot[n], 0, 0, 0);
            }
        }
        __syncthreads();
    }

    // ---- epilogue: normalize (one inv per lane) + store O^T ----
    const float inv = 1.f / srow;
#pragma unroll
    for (int n = 0; n < 4; n++)
#pragma unroll
        for (int r = 0; r < 4; r++) {
            int d = h * HD + 16 * n + 4 * g + r;
            Ot[(size_t)d * S_LEN + qbw + lr] = __float2bfloat16(ot[n][r] * inv);
        }
}

extern "C" void kernel_launch(void* const* d_in, const int* in_sizes, int n_in,
                              void* d_out, int out_size, void* d_ws, size_t ws_size,
                              hipStream_t stream) {
    const float* hs = (const float*)d_in[0];
    const float* Wq = (const float*)d_in[1];
    const float* Wk = (const float*)d_in[2];
    const float* Wv = (const float*)d_in[3];
    const float* Wo = (const float*)d_in[4];

    float* ws   = (float*)d_ws;
    float* cosT = ws;                  // 65536 f32
    float* sinT = cosT + 65536;        // 65536 f32
    __hip_bfloat16* hsb    = (__hip_bfloat16*)(sinT + 65536);   // [2048][2048]
    __hip_bfloat16* WqkvT  = hsb + 4194304;                     // [3072][2048]: Wq|Wk|Wv rows
    __hip_bfloat16* WoT    = WqkvT + 6291456;                   // [2048][2048]
    __hip_bfloat16* QKVb   = WoT + 4194304;                     // [2048][3072]
    __hip_bfloat16* Vt     = QKVb + 6291456;                    // [512][2048]
    __hip_bfloat16* Ot     = WqkvT;                             // alias: WqkvT dead after QKV gemm; [2048][2048] O^T
    __hip_bfloat16* Ab     = hsb;                               // alias: hsb dead after QKV gemm

    rope_table_kernel<<<(S_LEN * 32) / 256, 256, 0, stream>>>(cosT, sinT);
    conv_kernel<<<2048, 256, 0, stream>>>(hs, hsb);
    convT_kernel<<<dim3(64, 64), dim3(32, 8), 0, stream>>>(Wq, WqkvT, 2048, 2048, 2048);
    convT_kernel<<<dim3(16, 64), dim3(32, 8), 0, stream>>>(Wk, WqkvT + (size_t)2048 * 2048, 2048, 512, 2048);
    convT_kernel<<<dim3(16, 64), dim3(32, 8), 0, stream>>>(Wv, WqkvT + (size_t)2560 * 2048, 2048, 512, 2048);
    convT_kernel<<<dim3(64, 64), dim3(32, 8), 0, stream>>>(Wo, WoT, 2048, 2048, 2048);

    // fused QKV projection: [2048][3072] = hsb @ WqkvT^T
    gemm_pipe_kernel<1><<<384, 256, 0, stream>>>(hsb, WqkvT, QKVb, 2048, QKVN, 2048, 24);

    // RoPE on Q and K (fused QKV layout)
    rope_kernel<<<(S_LEN * (NH + NKV) * 32) / 256, 256, 0, stream>>>(QKVb, cosT, sinT);

    vtrans_kernel<<<dim3(64, 16), dim3(32, 8), 0, stream>>>(QKVb, Vt);

    attn_kernel<<<512, 512, 0, stream>>>(QKVb, QKVb + 2048, Vt, Ot);

    // restore row-major O for the Wo gemm
    otrans_kernel<<<dim3(64, 64), dim3(32, 8), 0, stream>>>(Ot, Ab);

    // output projection: d_out = Ab @ WoT^T
    gemm_pipe_kernel<0><<<256, 256, 0, stream>>>(Ab, WoT, d_out, 2048, 2048, 2048, 16);
}